// Round 8
// baseline (427.757 us; speedup 1.0000x reference)
//
#include <hip/hip_runtime.h>
#include <stdint.h>

// W8A8B32O32 Linear: y[m][n] = sum_k x[m][k]*w[n][k] + bias[n]
// M=8192, N=4096, K=4096. Inputs arrive as int32 (one int per logical int8
// element); pack to int8 in d_ws, then run the i8 MFMA GEMM.
#define M_TOT 8192
#define N_TOT 4096
#define K_TOT 4096

typedef int v4i  __attribute__((ext_vector_type(4)));
typedef int v16i __attribute__((ext_vector_type(16)));

__device__ __forceinline__ void gload_lds16(const void* g, void* l) {
    __builtin_amdgcn_global_load_lds(
        (const __attribute__((address_space(1))) unsigned int*)g,
        (__attribute__((address_space(3))) unsigned int*)l,
        16, 0, 0);
}

// gfx9 s_waitcnt simm16: vmcnt[3:0]@[3:0], expcnt@[6:4], lgkmcnt@[11:8],
// vmcnt[5:4]@[15:14].
#define WAIT_V6_L0() __builtin_amdgcn_s_waitcnt(0x0076)  // vmcnt(6) lgkmcnt(0)
#define WAIT_V0_L0() __builtin_amdgcn_s_waitcnt(0x0070)  // vmcnt(0) lgkmcnt(0)
#define WAIT_V8()    __builtin_amdgcn_s_waitcnt(0x0f78)  // vmcnt(8), lgkm free
#define SBAR()       __builtin_amdgcn_s_barrier()
#define SFENCE()     __builtin_amdgcn_sched_barrier(0)

// ---- fused pack int32 -> int8: 64B loads -> 16B store per thread-iter ----
// BW-bound at 240 MB (~45 us); split and fused variants measure the same ->
// already at the traffic floor.
__global__ __launch_bounds__(256) void pack2(
        const int4* __restrict__ xs, int4* __restrict__ xd,
        const int4* __restrict__ ws, int4* __restrict__ wd) {
    const int t = blockIdx.x * 256 + threadIdx.x;       // 0..524287
#pragma unroll
    for (int it = 0; it < 6; ++it) {
        const long g = (long)it * 524288 + t;
        const int4* __restrict__ src = (it < 4) ? xs : ws;
        int4* __restrict__ dst       = (it < 4) ? xd : wd;
        const long o = (it < 4) ? g : g - 2097152;
        int4 r;
        int* rp = (int*)&r;
#pragma unroll
        for (int q = 0; q < 4; ++q) {
            const int4 a = src[o * 4 + q];
            rp[q] = (a.x & 255) | ((a.y & 255) << 8) |
                    ((a.z & 255) << 16) | (a.w << 24);
        }
        dst[o] = r;
    }
}

// ---- GEMM: 512 threads = 8 waves (2/SIMD), 256x256 tile, BK=128 ----------
// R7 post-mortem: halving sync frequency (BK=128) was NEUTRAL (143.6 us,
// util 42.5%) -> per-sync overhead falsified. Ledger: per CU-iter wall 5386
// cyc = MFMA 2342 (per SIMD) + LDS pipe ~2800 (CU-shared: 192 ds_read_b128
// x 12 cyc structural + DMA writes) -- ADDITIVE under every schedule tried
// (R3/R4/R5/R7). Root cause is the read VOLUME: A read 4x, B 2x = 196 KB
// LDS reads per 64 KB staged.
//
// Fix (AITER flatmm pattern): B LEAVES LDS ENTIRELY. B fragments load
// per-lane global->VGPR: lane (l31,kh), wave (wc), frag j reads
// w[bn0+wc*64+j*32+l31][kt*128+kk*32+kh*16 .. +16] -- one dwordx4. Each
// 128-B W line is fully consumed by the wave (kh x kk cover it) and shared
// by the 2 wr-waves via L1 (per-CU B working set 32 KB = L1). LDS now
// serves A only: 128 reads + 32 KB writes ~= 1800 cyc/CU-iter < 2342 MFMA
// -> LDS leaves the critical path.
//
// Per K-iter (tile kt in cur, kt+1 -> nxt; kk = K-slice 0..3; b{k}[j] in
// VGPR, loaded 2+ phases ahead):
//   s0) 4 A-DMA tile kt+1 -> nxt
//   s1) 4 ds_read kk=1 -> a1       s2) 8 MFMA kk=0 (a0 x b0)
//   s3) 4 ds_read kk=2 -> a0       s4) 8 MFMA kk=1 (a1 x b1)
//   s4.5) load b0,b1 of kt+1 (4 global dwordx4)
//   s5) 4 ds_read kk=3 -> a1       s6) 8 MFMA kk=2 (a0 x b2)
//   s6.5) load b2 of kt+1 (2)
//   s7) s_waitcnt vmcnt(6) lgkmcnt(0); s_barrier
//       [drains the 4 A-DMAs (oldest after prev b3), keeps b01+b2 (6) in
//        flight; retires my LDS reads]
//   s8) 4 ds_read kk=0 of nxt -> a0
//   s9) 8 MFMA kk=3 (a1 x b3)
//   s9.5) load b3 of kt+1 (2); advance qb += 128
//   swap cur/nxt.
// vmcnt ledger at s7: outstanding (oldest first) = [b3_prev 2][DMA 4]
// [b01 4][b2 2] -> vmcnt(6) drains b3_prev+DMA4 exactly. b-loads are issued
// AFTER the DMAs each iter, so counted waits never trap them; compiler
// inserts its own vmcnt waits for b-register consumption (all >= ours).
// Buffer-reuse proof (A): s0 of iter kt writes nxt, last read at iter kt-1
// (s1..s5); iter kt-1's s7 lgkmcnt(0) retires those reads in EVERY wave
// before its barrier, and s0 is after. s8's reads of nxt follow this iter's
// s7 vmcnt drain + barrier. Explicit waits REQUIRED: compiler alias
// analysis does not connect global_load_lds's LDS write to the ds_reads.
// A staging (row-major, 128-B rows, 3-bit XOR chunk swizzle): stored_chunk
// = logical_chunk ^ (row&7); issue u covers rows u*8+(lane>>3), fetch chunk
// fc = (lane&7)^((lane>>3)&7); coalesced 128-B row segments, linear LDS dst.
__global__ __launch_bounds__(512, 2) void i8gemm_bias(
        const signed char* __restrict__ x,
        const signed char* __restrict__ w,
        const int* __restrict__ bias,
        int* __restrict__ out) {
    __shared__ __align__(16) signed char la[2][256 * 128];

    const int tid  = threadIdx.x;
    const int lane = tid & 63;           // 0..63
    const int wv   = tid >> 6;           // wave 0..7
    const int l31  = lane & 31;
    const int kh   = lane >> 5;          // K-half this lane supplies to MFMA
    const int wr   = wv >> 2;            // quadrant row (0..1) -> 128 rows
    const int wc   = wv & 3;             // quadrant col (0..3) -> 64 cols

    // XCD-aware bijective swizzle (512 blocks, 512%8==0): XCD k gets a
    // contiguous swz-range -> 4 A-panels x all 16 B-panels per XCD.
    const int flat = blockIdx.y * gridDim.x + blockIdx.x;   // 0..511
    const int swz  = (flat & 7) * 64 + (flat >> 3);
    const int bn0  = (swz & 15) * 256;
    const int bm0  = (swz >> 4) * 256;

    // Fused bias: C/D col = lane&31 -> bias is lane-constant per fragment.
    int bv[2];
#pragma unroll
    for (int j = 0; j < 2; ++j) bv[j] = bias[bn0 + wc * 64 + j * 32 + l31];
    v16i acc[4][2];
#pragma unroll
    for (int i = 0; i < 4; ++i)
#pragma unroll
        for (int j = 0; j < 2; ++j)
#pragma unroll
            for (int r = 0; r < 16; ++r) acc[i][j][r] = bv[j];

    // A staging: wave wv covers rows [wv*32, wv*32+32): 4 issues x (8 rows x
    // 8 chunks).
    const int fc = (lane & 7) ^ ((lane >> 3) & 7);
    const signed char* pa = x + (long)(bm0 + wv * 32 + (lane >> 3)) * K_TOT + fc * 16;
    const int sdst = wv * 32 * 128;      // + u*1024 per issue u

    // A fragment reads: row = wr*128 + i*32 + l31; swr = l31&7; logical
    // chunk kk*2+kh at slot (kk*2+kh)^swr.
    const int swr  = l31 & 7;
    const int aoff = (wr * 128 + l31) * 128;
    const int cs0 = ((0 + kh) ^ swr) * 16;
    const int cs1 = ((2 + kh) ^ swr) * 16;
    const int cs2 = ((4 + kh) ^ swr) * 16;
    const int cs3 = ((6 + kh) ^ swr) * 16;

    // B direct-load bases (per lane): row bn0 + wc*64 + j*32 + l31, byte
    // kh*16 within the current 128-B K-slab. Advanced += 128 per iter.
    const signed char* qb0 = w + (long)(bn0 + wc * 64 + l31) * K_TOT + kh * 16;
    const signed char* qb1 = qb0 + (long)32 * K_TOT;

    // Double buffer pointers (A only).
    signed char* A0 = &la[0][0]; signed char* A1 = &la[1][0];

    // Prologue: stage A tile 0 (4 DMAs), then b(iter0) (8 loads, AFTER the
    // DMAs so the vmcnt ledger stays [DMA oldest][b newer]).
#pragma unroll
    for (int u = 0; u < 4; ++u)
        gload_lds16(pa + (long)u * 8 * K_TOT, A0 + sdst + u * 1024);
    SFENCE();
    v4i b0[2], b1[2], b2[2], b3[2];
    b0[0] = *(const v4i*)(qb0);      b0[1] = *(const v4i*)(qb1);
    b1[0] = *(const v4i*)(qb0 + 32); b1[1] = *(const v4i*)(qb1 + 32);
    b2[0] = *(const v4i*)(qb0 + 64); b2[1] = *(const v4i*)(qb1 + 64);
    b3[0] = *(const v4i*)(qb0 + 96); b3[1] = *(const v4i*)(qb1 + 96);
    qb0 += 128; qb1 += 128;
    SFENCE();
    WAIT_V8();                 // A tile 0 landed; 8 b-loads stay in flight
    SBAR();
    SFENCE();

    // Preload kk=0 A fragments of tile 0 -> a0.
    v4i a0[4], a1[4];
#pragma unroll
    for (int i = 0; i < 4; ++i) a0[i] = *(const v4i*)(A0 + aoff + i * 4096 + cs0);

    const int NT = K_TOT / 128;          // 32 K-tiles
    for (int kt = 0; kt < NT; ++kt) {
        SFENCE();
        // s0) A-DMAs for tile kt+1.
        if (kt + 1 < NT) {
            const long k0 = (long)(kt + 1) * 128;
#pragma unroll
            for (int u = 0; u < 4; ++u)
                gload_lds16(pa + k0 + (long)u * 8 * K_TOT, A1 + sdst + u * 1024);
        }
        SFENCE();
        // s1) reads kk=1 -> a1.
#pragma unroll
        for (int i = 0; i < 4; ++i) a1[i] = *(const v4i*)(A0 + aoff + i * 4096 + cs1);
        SFENCE();
        // s2) MFMA kk=0.
        __builtin_amdgcn_s_setprio(1);
#pragma unroll
        for (int i = 0; i < 4; ++i)
#pragma unroll
            for (int j = 0; j < 2; ++j)
                acc[i][j] = __builtin_amdgcn_mfma_i32_32x32x32_i8(
                    a0[i], b0[j], acc[i][j], 0, 0, 0);
        __builtin_amdgcn_s_setprio(0);
        SFENCE();
        // s3) reads kk=2 -> a0.
#pragma unroll
        for (int i = 0; i < 4; ++i) a0[i] = *(const v4i*)(A0 + aoff + i * 4096 + cs2);
        SFENCE();
        // s4) MFMA kk=1.
        __builtin_amdgcn_s_setprio(1);
#pragma unroll
        for (int i = 0; i < 4; ++i)
#pragma unroll
            for (int j = 0; j < 2; ++j)
                acc[i][j] = __builtin_amdgcn_mfma_i32_32x32x32_i8(
                    a1[i], b1[j], acc[i][j], 0, 0, 0);
        __builtin_amdgcn_s_setprio(0);
        SFENCE();
        // s4.5) b0,b1 of tile kt+1 (dead after s2/s4).
        if (kt + 1 < NT) {
            b0[0] = *(const v4i*)(qb0);      b0[1] = *(const v4i*)(qb1);
            b1[0] = *(const v4i*)(qb0 + 32); b1[1] = *(const v4i*)(qb1 + 32);
        }
        SFENCE();
        // s5) reads kk=3 -> a1.
#pragma unroll
        for (int i = 0; i < 4; ++i) a1[i] = *(const v4i*)(A0 + aoff + i * 4096 + cs3);
        SFENCE();
        // s6) MFMA kk=2.
        __builtin_amdgcn_s_setprio(1);
#pragma unroll
        for (int i = 0; i < 4; ++i)
#pragma unroll
            for (int j = 0; j < 2; ++j)
                acc[i][j] = __builtin_amdgcn_mfma_i32_32x32x32_i8(
                    a0[i], b2[j], acc[i][j], 0, 0, 0);
        __builtin_amdgcn_s_setprio(0);
        SFENCE();
        // s6.5) b2 of tile kt+1.
        if (kt + 1 < NT) {
            b2[0] = *(const v4i*)(qb0 + 64); b2[1] = *(const v4i*)(qb1 + 64);
        }
        SFENCE();
        // s7) publish/acquire: A-DMAs drained, b01+b2 stay in flight.
        if (kt + 1 < NT) { WAIT_V6_L0(); } else { WAIT_V0_L0(); }
        SFENCE();
        SBAR();
        SFENCE();
        // s8) reads kk=0 of tile kt+1 (nxt) -> a0 (covered by s9).
        if (kt + 1 < NT) {
#pragma unroll
            for (int i = 0; i < 4; ++i) a0[i] = *(const v4i*)(A1 + aoff + i * 4096 + cs0);
        }
        SFENCE();
        // s9) MFMA kk=3.
        __builtin_amdgcn_s_setprio(1);
#pragma unroll
        for (int i = 0; i < 4; ++i)
#pragma unroll
            for (int j = 0; j < 2; ++j)
                acc[i][j] = __builtin_amdgcn_mfma_i32_32x32x32_i8(
                    a1[i], b3[j], acc[i][j], 0, 0, 0);
        __builtin_amdgcn_s_setprio(0);
        SFENCE();
        // s9.5) b3 of tile kt+1; advance B pointers.
        if (kt + 1 < NT) {
            b3[0] = *(const v4i*)(qb0 + 96); b3[1] = *(const v4i*)(qb1 + 96);
            qb0 += 128; qb1 += 128;
        }

        // Swap A double buffers (register pointer swap, no dynamic indexing).
        signed char* t = A0; A0 = A1; A1 = t;
    }

    // Epilogue: C/D layout col=lane&31, row=(reg&3)+8*(reg>>2)+4*(lane>>5).
#pragma unroll
    for (int i = 0; i < 4; ++i) {
        const int mbase = bm0 + wr * 128 + i * 32 + 4 * kh;
#pragma unroll
        for (int j = 0; j < 2; ++j) {
            const int n = bn0 + wc * 64 + j * 32 + l31;
#pragma unroll
            for (int r = 0; r < 16; ++r) {
                const int m = mbase + (r & 3) + 8 * (r >> 2);
                out[(long)m * N_TOT + n] = acc[i][j][r];
            }
        }
    }
}

extern "C" void kernel_launch(void* const* d_in, const int* in_sizes, int n_in,
                              void* d_out, int out_size, void* d_ws, size_t ws_size,
                              hipStream_t stream) {
    const int* x32  = (const int*)d_in[0];  // [8192,4096] logical i8 as i32
    const int* w32  = (const int*)d_in[1];  // [4096,4096] logical i8 as i32
    const int* bias = (const int*)d_in[2];  // [4096] i32
    int*       out  = (int*)d_out;          // [8192,4096] i32

    signed char* xp = (signed char*)d_ws;
    signed char* wp = (signed char*)d_ws + (size_t)M_TOT * K_TOT;

    pack2<<<2048, 256, 0, stream>>>((const int4*)x32, (int4*)xp,
                                    (const int4*)w32, (int4*)wp);

    dim3 grid(N_TOT / 256, M_TOT / 256);  // (16, 32)
    i8gemm_bias<<<grid, 512, 0, stream>>>(xp, wp, bias, out);
}

// Round 9
// 398.947 us; speedup vs baseline: 1.0722x; 1.0722x over previous
//
#include <hip/hip_runtime.h>
#include <stdint.h>

// W8A8B32O32 Linear: y[m][n] = sum_k x[m][k]*w[n][k] + bias[n]
// M=8192, N=4096, K=4096. Inputs arrive as int32 (one int per logical int8
// element); pack to int8 in d_ws (W additionally SHUFFLED to MFMA fragment
// order), then run the i8 MFMA GEMM with B streamed global->VGPR.
#define M_TOT 8192
#define N_TOT 4096
#define K_TOT 4096

typedef int v4i  __attribute__((ext_vector_type(4)));
typedef int v16i __attribute__((ext_vector_type(16)));

__device__ __forceinline__ void gload_lds16(const void* g, void* l) {
    __builtin_amdgcn_global_load_lds(
        (const __attribute__((address_space(1))) unsigned int*)g,
        (__attribute__((address_space(3))) unsigned int*)l,
        16, 0, 0);
}

// gfx9 s_waitcnt simm16: vmcnt[3:0]@[3:0], expcnt@[6:4], lgkmcnt@[11:8],
// vmcnt[5:4]@[15:14].
#define WAIT_V6_L0() __builtin_amdgcn_s_waitcnt(0x0076)  // vmcnt(6) lgkmcnt(0)
#define WAIT_V0_L0() __builtin_amdgcn_s_waitcnt(0x0070)  // vmcnt(0) lgkmcnt(0)
#define WAIT_V8()    __builtin_amdgcn_s_waitcnt(0x0f78)  // vmcnt(8), lgkm free
#define SBAR()       __builtin_amdgcn_s_barrier()
#define SFENCE()     __builtin_amdgcn_sched_barrier(0)

// ---- pack + shuffle ------------------------------------------------------
// x: plain pack (coalesced 64B loads -> 16B stores), unchanged.
// w: pack + SHUFFLE to flatmm fragment order. Output 16-B slot
//   q = ((nb*32 + kt)*8 + s)*32 + l31,  s = kk*2 + kh,
// holds w[nb*32 + l31][kt*128 + s*16 .. +16] as int8. A GEMM wave then reads
// B-frag (j,kk) as ONE contiguous 1-KB global_load_dwordx4 (addr = block
// base + lane*16). Thread mapping here is output-slot-major: consecutive
// threads -> consecutive slots => coalesced writes; reads are 64-B granules
// over 32 rows with L2 locality (R8 lesson: the GATHER pattern, not traffic,
// is what kills the VMEM path).
__global__ __launch_bounds__(256) void pack2(
        const int4* __restrict__ xs, int4* __restrict__ xd,
        const int4* __restrict__ ws, int4* __restrict__ wd) {
    const int t = blockIdx.x * 256 + threadIdx.x;       // 0..524287
    // x part: 4 iters x (4 int4 loads -> 1 int4 store), linear mapping.
#pragma unroll
    for (int it = 0; it < 4; ++it) {
        const long o = (long)it * 524288 + t;
        int4 r; int* rp = (int*)&r;
#pragma unroll
        for (int q = 0; q < 4; ++q) {
            const int4 a = xs[o * 4 + q];
            rp[q] = (a.x & 255) | ((a.y & 255) << 8) |
                    ((a.z & 255) << 16) | (a.w << 24);
        }
        xd[o] = r;
    }
    // w part: 2 iters, shuffled output slot q.
#pragma unroll
    for (int it = 0; it < 2; ++it) {
        const int q   = it * 524288 + t;       // 0..1048575
        const int l   = q & 31;                // lane / N-row within block
        const int s   = (q >> 5) & 7;          // k-chunk within 128-B slab
        const int ktb = (q >> 8) & 31;         // K-slab
        const int nb  = q >> 13;               // 32-row N-block
        const long src = (long)(nb * 32 + l) * 1024 + ktb * 32 + s * 4;
        int4 r; int* rp = (int*)&r;
#pragma unroll
        for (int qq = 0; qq < 4; ++qq) {
            const int4 a = ws[src + qq];
            rp[qq] = (a.x & 255) | ((a.y & 255) << 8) |
                     ((a.z & 255) << 16) | (a.w << 24);
        }
        wd[q] = r;
    }
}

// ---- GEMM: 512 threads = 8 waves (2/SIMD), 256x256 tile, BK=128 ----------
// R8 post-mortem: B-direct-global regressed (186us) because each b-load was
// a 32-cache-line GATHER (16B per lane at 4096-B row stride) -- FETCH_SIZE
// unchanged proved it was the VMEM pattern, not traffic. Session invariant:
// wall = MFMA + LDS time, ADDITIVE under every schedule (R3/4/5/7); only
// removing work from a pipe ever helped. This version keeps B out of LDS
// but loads it from the PRE-SHUFFLED w_s layout: B-frag (j,kk) of tile kt =
// contiguous 1 KB at blockbase(nb,kt,kk) + lane*16 -- as coalesced as the
// A-staging DMAs. LDS now serves A only: 64 wave-reads + 16 KB writes per
// CU-iter (~half of R7), well under the MFMA shadow.
//
// Per K-iter (A tile kt in cur, kt+1 -> nxt; kk = K-slice 0..3; b{kk}[j] in
// VGPR, loaded one tile ahead):
//   s0) 4 A-DMA tile kt+1 -> nxt
//   s1) 4 ds_read kk=1 -> a1       s2) 8 MFMA kk=0 (a0 x b0)
//   s3) 4 ds_read kk=2 -> a0       s4) 8 MFMA kk=1 (a1 x b1)
//   s4.5) load b0,b1 of kt+1 (4 x dwordx4, contiguous 1 KB each)
//   s5) 4 ds_read kk=3 -> a1       s6) 8 MFMA kk=2 (a0 x b2)
//   s6.5) load b2 of kt+1 (2)
//   s7) s_waitcnt vmcnt(6) lgkmcnt(0); s_barrier
//       [drains b3_prev + the 4 A-DMAs; keeps b01+b2 (6) in flight;
//        retires my LDS reads]
//   s8) 4 ds_read kk=0 of nxt -> a0
//   s9) 8 MFMA kk=3 (a1 x b3)
//   s9.5) load b3 of kt+1 (2); advance qb += 4096
//   swap cur/nxt.
// vmcnt ledger at s7: outstanding (oldest first) = [b3_prev 2][DMA 4]
// [b01 4][b2 2] -> vmcnt(6) drains b3_prev+DMA exactly; b-loads are issued
// AFTER the DMAs each iter so counted waits never trap them; the compiler
// inserts its own (larger) vmcnt waits for b-register consumption.
// Buffer-reuse proof (A): s0 of iter kt writes nxt, last read at iter kt-1
// (s1..s5); iter kt-1's s7 lgkmcnt(0) retires those reads in EVERY wave
// before its barrier, and s0 is after. s8's reads of nxt follow this iter's
// s7 vmcnt drain + barrier. Explicit waits REQUIRED: compiler alias
// analysis does not connect global_load_lds's LDS write to the ds_reads.
// A staging (row-major, 128-B rows, 3-bit XOR chunk swizzle): stored_chunk
// = logical_chunk ^ (row&7); issue u covers rows u*8+(lane>>3), fetch chunk
// fc = (lane&7)^((lane>>3)&7); coalesced 128-B row segments, linear LDS dst.
__global__ __launch_bounds__(512, 2) void i8gemm_bias(
        const signed char* __restrict__ x,
        const signed char* __restrict__ wshuf,
        const int* __restrict__ bias,
        int* __restrict__ out) {
    __shared__ __align__(16) signed char la[2][256 * 128];

    const int tid  = threadIdx.x;
    const int lane = tid & 63;           // 0..63
    const int wv   = tid >> 6;           // wave 0..7
    const int l31  = lane & 31;
    const int kh   = lane >> 5;          // K-half this lane supplies to MFMA
    const int wr   = wv >> 2;            // quadrant row (0..1) -> 128 rows
    const int wc   = wv & 3;             // quadrant col (0..3) -> 64 cols

    // XCD-aware bijective swizzle (512 blocks, 512%8==0).
    const int flat = blockIdx.y * gridDim.x + blockIdx.x;   // 0..511
    const int swz  = (flat & 7) * 64 + (flat >> 3);
    const int bn0  = (swz & 15) * 256;
    const int bm0  = (swz >> 4) * 256;

    // Fused bias: C/D col = lane&31 -> bias is lane-constant per fragment.
    int bv[2];
#pragma unroll
    for (int j = 0; j < 2; ++j) bv[j] = bias[bn0 + wc * 64 + j * 32 + l31];
    v16i acc[4][2];
#pragma unroll
    for (int i = 0; i < 4; ++i)
#pragma unroll
        for (int j = 0; j < 2; ++j)
#pragma unroll
            for (int r = 0; r < 16; ++r) acc[i][j][r] = bv[j];

    // A staging: wave wv covers rows [wv*32, wv*32+32): 4 issues x (8 rows x
    // 8 chunks).
    const int fc = (lane & 7) ^ ((lane >> 3) & 7);
    const signed char* pa = x + (long)(bm0 + wv * 32 + (lane >> 3)) * K_TOT + fc * 16;
    const int sdst = wv * 32 * 128;      // + u*1024 per issue u

    // A fragment reads: row = wr*128 + i*32 + l31; swr = l31&7; logical
    // chunk kk*2+kh at slot (kk*2+kh)^swr.
    const int swr  = l31 & 7;
    const int aoff = (wr * 128 + l31) * 128;
    const int cs0 = ((0 + kh) ^ swr) * 16;
    const int cs1 = ((2 + kh) ^ swr) * 16;
    const int cs2 = ((4 + kh) ^ swr) * 16;
    const int cs3 = ((6 + kh) ^ swr) * 16;

    // B shuffled-layout bases: frag j lives in N-block nbB+j; per (nb,kt)
    // there is a 4-KB block of 4 kk-slices x 1 KB; lane offset = lane*16.
    // Advance += 4096 per K-tile.
    const int nbB = (bn0 >> 5) + wc * 2;
    const signed char* qb0 = wshuf + (long)nbB * 131072 + lane * 16;
    const signed char* qb1 = qb0 + 131072;

    // Double buffer pointers (A only).
    signed char* A0 = &la[0][0]; signed char* A1 = &la[1][0];

    // Prologue: stage A tile 0 (4 DMAs), then b(iter0) (8 loads AFTER the
    // DMAs so the vmcnt ledger stays [DMA oldest][b newer]).
#pragma unroll
    for (int u = 0; u < 4; ++u)
        gload_lds16(pa + (long)u * 8 * K_TOT, A0 + sdst + u * 1024);
    SFENCE();
    v4i b0[2], b1[2], b2[2], b3[2];
    b0[0] = *(const v4i*)(qb0);        b0[1] = *(const v4i*)(qb1);
    b1[0] = *(const v4i*)(qb0 + 1024); b1[1] = *(const v4i*)(qb1 + 1024);
    b2[0] = *(const v4i*)(qb0 + 2048); b2[1] = *(const v4i*)(qb1 + 2048);
    b3[0] = *(const v4i*)(qb0 + 3072); b3[1] = *(const v4i*)(qb1 + 3072);
    qb0 += 4096; qb1 += 4096;
    SFENCE();
    WAIT_V8();                 // A tile 0 landed; 8 b-loads stay in flight
    SBAR();
    SFENCE();

    // Preload kk=0 A fragments of tile 0 -> a0.
    v4i a0[4], a1[4];
#pragma unroll
    for (int i = 0; i < 4; ++i) a0[i] = *(const v4i*)(A0 + aoff + i * 4096 + cs0);

    const int NT = K_TOT / 128;          // 32 K-tiles
    for (int kt = 0; kt < NT; ++kt) {
        SFENCE();
        // s0) A-DMAs for tile kt+1.
        if (kt + 1 < NT) {
            const long k0 = (long)(kt + 1) * 128;
#pragma unroll
            for (int u = 0; u < 4; ++u)
                gload_lds16(pa + k0 + (long)u * 8 * K_TOT, A1 + sdst + u * 1024);
        }
        SFENCE();
        // s1) reads kk=1 -> a1.
#pragma unroll
        for (int i = 0; i < 4; ++i) a1[i] = *(const v4i*)(A0 + aoff + i * 4096 + cs1);
        SFENCE();
        // s2) MFMA kk=0.
        __builtin_amdgcn_s_setprio(1);
#pragma unroll
        for (int i = 0; i < 4; ++i)
#pragma unroll
            for (int j = 0; j < 2; ++j)
                acc[i][j] = __builtin_amdgcn_mfma_i32_32x32x32_i8(
                    a0[i], b0[j], acc[i][j], 0, 0, 0);
        __builtin_amdgcn_s_setprio(0);
        SFENCE();
        // s3) reads kk=2 -> a0.
#pragma unroll
        for (int i = 0; i < 4; ++i) a0[i] = *(const v4i*)(A0 + aoff + i * 4096 + cs2);
        SFENCE();
        // s4) MFMA kk=1.
        __builtin_amdgcn_s_setprio(1);
#pragma unroll
        for (int i = 0; i < 4; ++i)
#pragma unroll
            for (int j = 0; j < 2; ++j)
                acc[i][j] = __builtin_amdgcn_mfma_i32_32x32x32_i8(
                    a1[i], b1[j], acc[i][j], 0, 0, 0);
        __builtin_amdgcn_s_setprio(0);
        SFENCE();
        // s4.5) b0,b1 of tile kt+1 (dead after s2/s4) -- contiguous 1 KB each.
        if (kt + 1 < NT) {
            b0[0] = *(const v4i*)(qb0);        b0[1] = *(const v4i*)(qb1);
            b1[0] = *(const v4i*)(qb0 + 1024); b1[1] = *(const v4i*)(qb1 + 1024);
        }
        SFENCE();
        // s5) reads kk=3 -> a1.
#pragma unroll
        for (int i = 0; i < 4; ++i) a1[i] = *(const v4i*)(A0 + aoff + i * 4096 + cs3);
        SFENCE();
        // s6) MFMA kk=2.
        __builtin_amdgcn_s_setprio(1);
#pragma unroll
        for (int i = 0; i < 4; ++i)
#pragma unroll
            for (int j = 0; j < 2; ++j)
                acc[i][j] = __builtin_amdgcn_mfma_i32_32x32x32_i8(
                    a0[i], b2[j], acc[i][j], 0, 0, 0);
        __builtin_amdgcn_s_setprio(0);
        SFENCE();
        // s6.5) b2 of tile kt+1.
        if (kt + 1 < NT) {
            b2[0] = *(const v4i*)(qb0 + 2048); b2[1] = *(const v4i*)(qb1 + 2048);
        }
        SFENCE();
        // s7) publish/acquire: b3_prev + A-DMAs drained, b01+b2 in flight.
        if (kt + 1 < NT) { WAIT_V6_L0(); } else { WAIT_V0_L0(); }
        SFENCE();
        SBAR();
        SFENCE();
        // s8) reads kk=0 of tile kt+1 (nxt) -> a0 (covered by s9).
        if (kt + 1 < NT) {
#pragma unroll
            for (int i = 0; i < 4; ++i) a0[i] = *(const v4i*)(A1 + aoff + i * 4096 + cs0);
        }
        SFENCE();
        // s9) MFMA kk=3.
        __builtin_amdgcn_s_setprio(1);
#pragma unroll
        for (int i = 0; i < 4; ++i)
#pragma unroll
            for (int j = 0; j < 2; ++j)
                acc[i][j] = __builtin_amdgcn_mfma_i32_32x32x32_i8(
                    a1[i], b3[j], acc[i][j], 0, 0, 0);
        __builtin_amdgcn_s_setprio(0);
        SFENCE();
        // s9.5) b3 of tile kt+1; advance B pointers.
        if (kt + 1 < NT) {
            b3[0] = *(const v4i*)(qb0 + 3072); b3[1] = *(const v4i*)(qb1 + 3072);
            qb0 += 4096; qb1 += 4096;
        }

        // Swap A double buffers (register pointer swap, no dynamic indexing).
        signed char* t = A0; A0 = A1; A1 = t;
    }

    // Epilogue: C/D layout col=lane&31, row=(reg&3)+8*(reg>>2)+4*(lane>>5).
#pragma unroll
    for (int i = 0; i < 4; ++i) {
        const int mbase = bm0 + wr * 128 + i * 32 + 4 * kh;
#pragma unroll
        for (int j = 0; j < 2; ++j) {
            const int n = bn0 + wc * 64 + j * 32 + l31;
#pragma unroll
            for (int r = 0; r < 16; ++r) {
                const int m = mbase + (r & 3) + 8 * (r >> 2);
                out[(long)m * N_TOT + n] = acc[i][j][r];
            }
        }
    }
}

extern "C" void kernel_launch(void* const* d_in, const int* in_sizes, int n_in,
                              void* d_out, int out_size, void* d_ws, size_t ws_size,
                              hipStream_t stream) {
    const int* x32  = (const int*)d_in[0];  // [8192,4096] logical i8 as i32
    const int* w32  = (const int*)d_in[1];  // [4096,4096] logical i8 as i32
    const int* bias = (const int*)d_in[2];  // [4096] i32
    int*       out  = (int*)d_out;          // [8192,4096] i32

    signed char* xp = (signed char*)d_ws;
    signed char* wp = (signed char*)d_ws + (size_t)M_TOT * K_TOT;

    pack2<<<2048, 256, 0, stream>>>((const int4*)x32, (int4*)xp,
                                    (const int4*)w32, (int4*)wp);

    dim3 grid(N_TOT / 256, M_TOT / 256);  // (16, 32)
    i8gemm_bias<<<grid, 512, 0, stream>>>(xp, wp, bias, out);
}

// Round 10
// 395.700 us; speedup vs baseline: 1.0810x; 1.0082x over previous
//
#include <hip/hip_runtime.h>
#include <stdint.h>

// W8A8B32O32 Linear: y[m][n] = sum_k x[m][k]*w[n][k] + bias[n]
// M=8192, N=4096, K=4096. Inputs arrive as int32 (one int per logical int8
// element); pack to int8 in d_ws (W additionally SHUFFLED to MFMA fragment
// order), then run the i8 MFMA GEMM with B streamed global->VGPR.
#define M_TOT 8192
#define N_TOT 4096
#define K_TOT 4096

typedef int v4i  __attribute__((ext_vector_type(4)));
typedef int v16i __attribute__((ext_vector_type(16)));

__device__ __forceinline__ void gload_lds16(const void* g, void* l) {
    __builtin_amdgcn_global_load_lds(
        (const __attribute__((address_space(1))) unsigned int*)g,
        (__attribute__((address_space(3))) unsigned int*)l,
        16, 0, 0);
}

// gfx9 s_waitcnt simm16: vmcnt[3:0]@[3:0], expcnt@[6:4], lgkmcnt@[11:8],
// vmcnt[5:4]@[15:14].
#define WAIT_V6_L0() __builtin_amdgcn_s_waitcnt(0x0076)  // vmcnt(6) lgkmcnt(0)
#define WAIT_V0_L0() __builtin_amdgcn_s_waitcnt(0x0070)  // vmcnt(0) lgkmcnt(0)
#define WAIT_V8()    __builtin_amdgcn_s_waitcnt(0x0f78)  // vmcnt(8), lgkm free
#define SBAR()       __builtin_amdgcn_s_barrier()
#define SFENCE()     __builtin_amdgcn_sched_barrier(0)

// ---- pack + shuffle (unchanged from R9, proven correct) ------------------
// x: plain pack. w: pack + shuffle to flatmm fragment order: 16-B slot
// q = ((nb*32 + kt)*8 + s)*32 + l31 (s = kk*2+kh) holds
// w[nb*32+l31][kt*128 + s*16 .. +16] -> B-frag (j,kk) = one contiguous 1-KB
// global_load_dwordx4 in the GEMM.
__global__ __launch_bounds__(256) void pack2(
        const int4* __restrict__ xs, int4* __restrict__ xd,
        const int4* __restrict__ ws, int4* __restrict__ wd) {
    const int t = blockIdx.x * 256 + threadIdx.x;       // 0..524287
#pragma unroll
    for (int it = 0; it < 4; ++it) {
        const long o = (long)it * 524288 + t;
        int4 r; int* rp = (int*)&r;
#pragma unroll
        for (int q = 0; q < 4; ++q) {
            const int4 a = xs[o * 4 + q];
            rp[q] = (a.x & 255) | ((a.y & 255) << 8) |
                    ((a.z & 255) << 16) | (a.w << 24);
        }
        xd[o] = r;
    }
#pragma unroll
    for (int it = 0; it < 2; ++it) {
        const int q   = it * 524288 + t;       // 0..1048575
        const int l   = q & 31;
        const int s   = (q >> 5) & 7;
        const int ktb = (q >> 8) & 31;
        const int nb  = q >> 13;
        const long src = (long)(nb * 32 + l) * 1024 + ktb * 32 + s * 4;
        int4 r; int* rp = (int*)&r;
#pragma unroll
        for (int qq = 0; qq < 4; ++qq) {
            const int4 a = ws[src + qq];
            rp[qq] = (a.x & 255) | ((a.y & 255) << 8) |
                     ((a.z & 255) << 16) | (a.w << 24);
        }
        wd[q] = r;
    }
}

// ---- GEMM: 512 threads = 8 waves (2/SIMD), 256x256 tile, BK=128 ----------
// R9 post-mortem: halving LDS traffic (B->global, coalesced) was NEUTRAL
// (144.8us, util 43%, conflicts 12.6M->8.4M as predicted). Combined with
// R7 (sync rate neutral) and R2 (latency depth neutral): the wall is NOT
// pipe occupancy. Surviving theory: INTRA-SIMD PHASE COLLISION -- both
// waves of a SIMD run the same program from the same barrier, so their
// read bursts and MFMA clusters coincide; pipe duty = MFMA/(MFMA+read
// window) ~= 50%, matching 42-48% across every structure tried.
//
// Fix: ANTIPHASE WAVE PAIRING. Even waves: [read slice k+1 -> MFMA slice k]
// per phase. Odd waves: [MFMA slice k -> read slice k+2], with TWO slices
// preloaded at loop entry (read-use distance stays 1 phase). One wave's
// MFMA cluster covers the other's read-return window. Barrier count and
// per-wave VMEM ISSUE ORDER are identical in both paths, so the counted
// vmcnt ledger and all publish proofs are unchanged from R9:
//   vmcnt at wait: [b3_prev 2][A-DMA 4][b01 4][b2 2] -> vmcnt(6) drains
//   b3_prev + the 4 A-DMAs exactly; lgkmcnt(0) retires this wave's LDS
//   reads of cur; barrier publishes nxt (A) block-wide. DMAs into a buffer
//   only ever follow the lgkmcnt(0)+barrier that retired ALL waves' reads
//   of it. Explicit waits REQUIRED: compiler alias analysis does not
//   connect global_load_lds's LDS write to the ds_reads.
// A staging (row-major, 128-B rows, 3-bit XOR chunk swizzle): stored_chunk
// = logical_chunk ^ (row&7); issue u covers rows u*8+(lane>>3), fetch chunk
// fc = (lane&7)^((lane>>3)&7); coalesced 128-B segments, linear LDS dst.

#define READ_A(dst, BUF, CS) do {                                          \
    _Pragma("unroll")                                                      \
    for (int i = 0; i < 4; ++i)                                            \
        dst[i] = *(const v4i*)((BUF) + aoff + i * 4096 + (CS));            \
} while (0)

#define MFMA_8(AF, BF) do {                                                \
    __builtin_amdgcn_s_setprio(1);                                         \
    _Pragma("unroll")                                                      \
    for (int i = 0; i < 4; ++i)                                            \
        _Pragma("unroll")                                                  \
        for (int j = 0; j < 2; ++j)                                        \
            acc[i][j] = __builtin_amdgcn_mfma_i32_32x32x32_i8(             \
                AF[i], BF[j], acc[i][j], 0, 0, 0);                         \
    __builtin_amdgcn_s_setprio(0);                                         \
} while (0)

#define DMA_A_NXT() do {                                                   \
    if (kt + 1 < NT) {                                                     \
        const long k0 = (long)(kt + 1) * 128;                              \
        _Pragma("unroll")                                                  \
        for (int u = 0; u < 4; ++u)                                        \
            gload_lds16(pa + k0 + (long)u * 8 * K_TOT,                     \
                        A1 + sdst + u * 1024);                             \
    }                                                                      \
} while (0)

#define LOAD_B01() do {                                                    \
    if (kt + 1 < NT) {                                                     \
        b0[0] = *(const v4i*)(qb0);        b0[1] = *(const v4i*)(qb1);     \
        b1[0] = *(const v4i*)(qb0 + 1024); b1[1] = *(const v4i*)(qb1 + 1024); \
    }                                                                      \
} while (0)

#define LOAD_B2() do {                                                     \
    if (kt + 1 < NT) {                                                     \
        b2[0] = *(const v4i*)(qb0 + 2048); b2[1] = *(const v4i*)(qb1 + 2048); \
    }                                                                      \
} while (0)

#define LOAD_B3_ADV() do {                                                 \
    if (kt + 1 < NT) {                                                     \
        b3[0] = *(const v4i*)(qb0 + 3072); b3[1] = *(const v4i*)(qb1 + 3072); \
        qb0 += 4096; qb1 += 4096;                                          \
    }                                                                      \
} while (0)

#define WAIT_PUB() do {                                                    \
    if (kt + 1 < NT) { WAIT_V6_L0(); } else { WAIT_V0_L0(); }              \
    SFENCE();                                                              \
    SBAR();                                                                \
} while (0)

__global__ __launch_bounds__(512, 2) void i8gemm_bias(
        const signed char* __restrict__ x,
        const signed char* __restrict__ wshuf,
        const int* __restrict__ bias,
        int* __restrict__ out) {
    __shared__ __align__(16) signed char la[2][256 * 128];

    const int tid  = threadIdx.x;
    const int lane = tid & 63;           // 0..63
    const int wv   = tid >> 6;           // wave 0..7
    const int l31  = lane & 31;
    const int kh   = lane >> 5;          // K-half this lane supplies to MFMA
    const int wr   = wv >> 2;            // quadrant row (0..1) -> 128 rows
    const int wc   = wv & 3;             // quadrant col (0..3) -> 64 cols

    // XCD-aware bijective swizzle (512 blocks, 512%8==0).
    const int flat = blockIdx.y * gridDim.x + blockIdx.x;   // 0..511
    const int swz  = (flat & 7) * 64 + (flat >> 3);
    const int bn0  = (swz & 15) * 256;
    const int bm0  = (swz >> 4) * 256;

    // Fused bias: C/D col = lane&31 -> bias is lane-constant per fragment.
    int bv[2];
#pragma unroll
    for (int j = 0; j < 2; ++j) bv[j] = bias[bn0 + wc * 64 + j * 32 + l31];
    v16i acc[4][2];
#pragma unroll
    for (int i = 0; i < 4; ++i)
#pragma unroll
        for (int j = 0; j < 2; ++j)
#pragma unroll
            for (int r = 0; r < 16; ++r) acc[i][j][r] = bv[j];

    // A staging: wave wv covers rows [wv*32, wv*32+32): 4 issues x (8 rows x
    // 8 chunks).
    const int fc = (lane & 7) ^ ((lane >> 3) & 7);
    const signed char* pa = x + (long)(bm0 + wv * 32 + (lane >> 3)) * K_TOT + fc * 16;
    const int sdst = wv * 32 * 128;      // + u*1024 per issue u

    // A fragment reads: row = wr*128 + i*32 + l31; swr = l31&7; logical
    // chunk kk*2+kh at slot (kk*2+kh)^swr.
    const int swr  = l31 & 7;
    const int aoff = (wr * 128 + l31) * 128;
    const int cs0 = ((0 + kh) ^ swr) * 16;
    const int cs1 = ((2 + kh) ^ swr) * 16;
    const int cs2 = ((4 + kh) ^ swr) * 16;
    const int cs3 = ((6 + kh) ^ swr) * 16;

    // B shuffled-layout bases: frag j in N-block nbB+j; per (nb,kt) a 4-KB
    // block of 4 kk-slices x 1 KB; lane offset = lane*16. += 4096 per tile.
    const int nbB = (bn0 >> 5) + wc * 2;
    const signed char* qb0 = wshuf + (long)nbB * 131072 + lane * 16;
    const signed char* qb1 = qb0 + 131072;

    // Double buffer pointers (A only).
    signed char* A0 = &la[0][0]; signed char* A1 = &la[1][0];

    // Prologue: stage A tile 0 (4 DMAs), then b(iter0) (8 loads AFTER the
    // DMAs so the vmcnt ledger stays [DMA oldest][b newer]).
#pragma unroll
    for (int u = 0; u < 4; ++u)
        gload_lds16(pa + (long)u * 8 * K_TOT, A0 + sdst + u * 1024);
    SFENCE();
    v4i b0[2], b1[2], b2[2], b3[2];
    b0[0] = *(const v4i*)(qb0);        b0[1] = *(const v4i*)(qb1);
    b1[0] = *(const v4i*)(qb0 + 1024); b1[1] = *(const v4i*)(qb1 + 1024);
    b2[0] = *(const v4i*)(qb0 + 2048); b2[1] = *(const v4i*)(qb1 + 2048);
    b3[0] = *(const v4i*)(qb0 + 3072); b3[1] = *(const v4i*)(qb1 + 3072);
    qb0 += 4096; qb1 += 4096;
    SFENCE();
    WAIT_V8();                 // A tile 0 landed; 8 b-loads stay in flight
    SBAR();
    SFENCE();

    v4i a0[4], a1[4];
    READ_A(a0, A0, cs0);                 // all waves: kk=0 -> a0
    if (wv & 1) READ_A(a1, A0, cs1);     // odd waves: kk=1 -> a1 (2-deep)

    const int NT = K_TOT / 128;          // 32 K-tiles

    if ((wv & 1) == 0) {
        // ---------------- EVEN waves: read-then-MFMA ----------------
        for (int kt = 0; kt < NT; ++kt) {
            SFENCE();
            DMA_A_NXT();                 SFENCE();
            READ_A(a1, A0, cs1);         SFENCE();   // kk=1
            MFMA_8(a0, b0);              SFENCE();   // kk=0
            READ_A(a0, A0, cs2);         SFENCE();   // kk=2
            MFMA_8(a1, b1);              SFENCE();   // kk=1
            LOAD_B01();                  SFENCE();
            READ_A(a1, A0, cs3);         SFENCE();   // kk=3
            MFMA_8(a0, b2);              SFENCE();   // kk=2
            LOAD_B2();                   SFENCE();
            WAIT_PUB();                  SFENCE();
            if (kt + 1 < NT) { READ_A(a0, A1, cs0); } SFENCE();  // kk=0'
            MFMA_8(a1, b3);              SFENCE();   // kk=3
            LOAD_B3_ADV();
            signed char* t = A0; A0 = A1; A1 = t;
        }
    } else {
        // ---------------- ODD waves: MFMA-then-read (antiphase) -----
        // Invariant at loop top: a0 = kk0(cur), a1 = kk1(cur).
        for (int kt = 0; kt < NT; ++kt) {
            SFENCE();
            DMA_A_NXT();                 SFENCE();
            MFMA_8(a0, b0);              SFENCE();   // kk=0
            READ_A(a0, A0, cs2);         SFENCE();   // kk=2
            MFMA_8(a1, b1);              SFENCE();   // kk=1
            LOAD_B01();                  SFENCE();
            READ_A(a1, A0, cs3);         SFENCE();   // kk=3
            MFMA_8(a0, b2);              SFENCE();   // kk=2 (covered by kk=1)
            LOAD_B2();                   SFENCE();
            WAIT_PUB();                  SFENCE();
            MFMA_8(a1, b3);              SFENCE();   // kk=3
            LOAD_B3_ADV();               SFENCE();
            if (kt + 1 < NT) {                       // preload 2 slices of nxt
                READ_A(a0, A1, cs0);
                READ_A(a1, A1, cs1);
            }
            signed char* t = A0; A0 = A1; A1 = t;
        }
    }

    // Epilogue: C/D layout col=lane&31, row=(reg&3)+8*(reg>>2)+4*(lane>>5).
#pragma unroll
    for (int i = 0; i < 4; ++i) {
        const int mbase = bm0 + wr * 128 + i * 32 + 4 * kh;
#pragma unroll
        for (int j = 0; j < 2; ++j) {
            const int n = bn0 + wc * 64 + j * 32 + l31;
#pragma unroll
            for (int r = 0; r < 16; ++r) {
                const int m = mbase + (r & 3) + 8 * (r >> 2);
                out[(long)m * N_TOT + n] = acc[i][j][r];
            }
        }
    }
}

extern "C" void kernel_launch(void* const* d_in, const int* in_sizes, int n_in,
                              void* d_out, int out_size, void* d_ws, size_t ws_size,
                              hipStream_t stream) {
    const int* x32  = (const int*)d_in[0];  // [8192,4096] logical i8 as i32
    const int* w32  = (const int*)d_in[1];  // [4096,4096] logical i8 as i32
    const int* bias = (const int*)d_in[2];  // [4096] i32
    int*       out  = (int*)d_out;          // [8192,4096] i32

    signed char* xp = (signed char*)d_ws;
    signed char* wp = (signed char*)d_ws + (size_t)M_TOT * K_TOT;

    pack2<<<2048, 256, 0, stream>>>((const int4*)x32, (int4*)xp,
                                    (const int4*)w32, (int4*)wp);

    dim3 grid(N_TOT / 256, M_TOT / 256);  // (16, 32)
    i8gemm_bias<<<grid, 512, 0, stream>>>(xp, wp, bias, out);
}